// Round 8
// baseline (763.526 us; speedup 1.0000x reference)
//
#include <hip/hip_runtime.h>

#define BROWS  32768
#define DDIM   512
#define NCODES 8192
#define NCHUNK 4
#define CHUNKN (NCODES / NCHUNK)   // 2048
#define NSPLIT2 64                 // stage-2 N-splits
#define CHUNK2 (NCODES / NSPLIT2)  // 128
#define NF_CAP 8192                // stage-2 row-slot capacity (nf expected ~1900)
#define TM     128
#define TN     128
#define BK     32
#define NKT    (DDIM / BK)         // 16
#define NS1    ((CHUNKN / TN) * NKT)  // 256 fused K-steps in gemm1
#define MARGIN1 6.0e-4f            // stage-1 (hh-only) pair-error bound, ~6 sigma
#define MARGIN  6e-6f              // stage-2 (bf16x2 3-MFMA) error bound

typedef unsigned short ushort_t;
typedef unsigned int   uint_t;
typedef unsigned long long ull_t;
typedef __attribute__((ext_vector_type(8))) short  short8;
typedef __attribute__((ext_vector_type(4))) float  floatx4;

__device__ __forceinline__ float wave_sum(float v) {
#pragma unroll
  for (int o = 32; o > 0; o >>= 1) v += __shfl_xor(v, o, 64);
  return v;
}

__device__ __forceinline__ floatx4 mfma16(short8 a, short8 b, floatx4 c) {
  return __builtin_amdgcn_mfma_f32_16x16x32_bf16(a, b, c, 0, 0, 0);
}

// async global->LDS, 16B per lane; lds dst is wave-uniform base + lane*16 (HW rule)
__device__ __forceinline__ void ld2lds16(const ushort_t* g, ushort_t* l) {
  __builtin_amdgcn_global_load_lds((__attribute__((address_space(1))) void*)g,
                                   (__attribute__((address_space(3))) void*)l,
                                   16, 0, 0);
}

__device__ __forceinline__ void split1(float v, ushort_t& h, ushort_t& l) {
  uint_t u  = __float_as_uint(v);
  uint_t hb = (u + 0x7FFFu + ((u >> 16) & 1u)) >> 16;   // RNE
  h = (ushort_t)hb;
  float r = v - __uint_as_float(hb << 16);               // exact (Sterbenz)
  uint_t u2 = __float_as_uint(r);
  l = (ushort_t)((u2 + 0x7FFFu + ((u2 >> 16) & 1u)) >> 16);
}

// ordered-uint pack: key orders by value, then by LOWER index (tie-break)
__device__ __forceinline__ ull_t pack_key(float v, int c) {
  uint_t u = __float_as_uint(v);
  u = (u & 0x80000000u) ? ~u : (u | 0x80000000u);
  return ((ull_t)u << 32) | (uint_t)(NCODES - 1 - c);
}

// Normalize rows of x (4 rows/block, wave per row); write fp32 (optional) + bf16 hi/lo.
__global__ __launch_bounds__(256) void prep_split_kernel(const float* __restrict__ x,
                                                         float* __restrict__ xn,
                                                         ushort_t* __restrict__ xh,
                                                         ushort_t* __restrict__ xl) {
  const int w = threadIdx.x >> 6, lane = threadIdx.x & 63;
  const size_t row = (size_t)blockIdx.x * 4 + w;
  const float4* src = (const float4*)(x + row * DDIM);
  float4 a = src[lane], b = src[lane + 64];
  float s = a.x*a.x + a.y*a.y + a.z*a.z + a.w*a.w
          + b.x*b.x + b.y*b.y + b.z*b.z + b.w*b.w;
  s = wave_sum(s);
  const float inv = 1.0f / fmaxf(sqrtf(s), 1e-12f);
  a.x *= inv; a.y *= inv; a.z *= inv; a.w *= inv;
  b.x *= inv; b.y *= inv; b.z *= inv; b.w *= inv;
  if (xn) {
    float4* dst = (float4*)(xn + row * DDIM);
    dst[lane] = a; dst[lane + 64] = b;
  }
  ushort4 h0, l0, h1, l1;
  split1(a.x, h0.x, l0.x); split1(a.y, h0.y, l0.y);
  split1(a.z, h0.z, l0.z); split1(a.w, h0.w, l0.w);
  split1(b.x, h1.x, l1.x); split1(b.y, h1.y, l1.y);
  split1(b.z, h1.z, l1.z); split1(b.w, h1.w, l1.w);
  ushort4* ph = (ushort4*)(xh + row * DDIM);
  ushort4* pl = (ushort4*)(xl + row * DDIM);
  ph[lane] = h0; ph[lane + 64] = h1;
  pl[lane] = l0; pl[lane + 64] = l1;
}

// Fragment read: single ds_read_b128 at the XOR-swizzled 16B chunk position.
__device__ __forceinline__ short8 frag_read(const ushort_t* base, int off16) {
  return *(const short8*)(base + off16);
}

// ---------------- stage 1: hh-only (1-MFMA) screening GEMM ----------------
// R6 diagnosis: ~1830 cyc/K-step vs 78 cyc MFMA content -> latency-bound on the
// per-step vmcnt(0) drain (2-buffer loops MUST drain-0 at the barrier).
// Fix A (T4): 3-deep LDS pipeline + counted vmcnt: at step s, issue loads for
//   s+2, wait vmcnt(4) (s+1's 4 loads landed, s+2's stay in flight) + raw
//   s_barrier + sched_barrier(0). All waves share issue order, so per-wave
//   vmcnt + barrier => global landing. buf[s%3] rewritten only by issue(s+3),
//   which is after the step-s barrier -> no race. ct loop fused into one
//   256-step stream (kills 16 prologue drains).
// Fix B (T1): XCD-aware remap: each XCD owns one (chunk, row-half): its 2 MB
//   eh slice stays L2-resident.
// (256,2): R4 measured (256,3) spills (VGPR 128->84, scratch 169MB). Keep 2.
__global__ __launch_bounds__(256, 2) void gemm1_kernel(
    const ushort_t* __restrict__ zh, const ushort_t* __restrict__ eh,
    float* __restrict__ pv1, int* __restrict__ pi1, float* __restrict__ pv2) {
  __shared__ union {
    ushort_t stg[3][2][TM * BK];                         // 3 bufs x (Ah Bh) = 48 KB
    struct { float v1[TM][2]; float v2[TM][2]; int i1[TM][2]; } red;  // 3 KB
  } u;
  const int t = threadIdx.x;
  const int w = t >> 6;            // wave 0..3
  const int lane = t & 63;
  const int wm = w >> 1, wn = w & 1;
  const int col = lane & 15;
  const int quad = lane >> 4;

  // XCD-aware remap (bijective, nwg=1024): xcd = lin&7 owns chunk=xcd>>1 and
  // row-half=xcd&1 -> B slice (2MB) L2-resident per XCD.
  const int lin = blockIdx.y * NCHUNK + blockIdx.x;
  const int xcd = lin & 7, bidx = lin >> 3;
  const int chunk = xcd >> 1;
  const int row0 = ((xcd & 1) * 128 + bidx) * TM;

  // staging: lane l -> row (l>>2), swizzled chunk (l&3)^((l>>3)&3)
  const int swc = ((lane & 3) ^ ((lane >> 3) & 3)) * 8;
  const int matsel = w >> 1;       // 0: stage Ah, 1: stage Bh
  const int half = w & 1;          // row-half 0..63 / 64..127
  const ushort_t* gsrcA = zh + (size_t)(row0 + half * 64 + (lane >> 2)) * DDIM + swc;
  const ushort_t* gsrcB0 = eh + (size_t)(chunk * CHUNKN + half * 64 + (lane >> 2)) * DDIM + swc;

  // fragment-read swizzle: 16B chunk (quad ^ ((col>>1)&3))
  const int swr = (quad ^ ((col >> 1) & 3)) * 8;

  float tv1[16], tv2[16]; int ti1[16];
#pragma unroll
  for (int s = 0; s < 16; ++s) { tv1[s] = -3.0e38f; tv2[s] = -3.0e38f; ti1[s] = 0; }

  floatx4 acc[4][4];
  const floatx4 z4 = {0.f, 0.f, 0.f, 0.f};
#pragma unroll
  for (int i = 0; i < 4; ++i)
#pragma unroll
    for (int j = 0; j < 4; ++j) acc[i][j] = z4;

  // issue the 4 staging loads for fused step s (ct = s>>4, kt = s&15)
  auto issue = [&](int s) {
    const int ct = s >> 4, kt = s & 15;
    const ushort_t* g = (matsel == 0)
        ? gsrcA + (kt << 5)
        : gsrcB0 + ((size_t)ct << 16) + (kt << 5);   // ct*TN*DDIM = ct*65536
    ushort_t* l0 = u.stg[s % 3][matsel] + half * 2048;
#pragma unroll
    for (int i = 0; i < 4; ++i)
      ld2lds16(g + (size_t)(i * 16) * DDIM, l0 + i * 512);
  };

  issue(0); issue(1);
  asm volatile("s_waitcnt vmcnt(4)" ::: "memory");   // step-0 loads landed
  __builtin_amdgcn_s_barrier();
  __builtin_amdgcn_sched_barrier(0);

  for (int s = 0; s < NS1; ++s) {
    if (s + 2 < NS1) issue(s + 2);

    const ushort_t* bA = u.stg[s % 3][0];
    const ushort_t* bB = u.stg[s % 3][1];
    short8 ah[4], bh[4];
#pragma unroll
    for (int i = 0; i < 4; ++i) {
      ah[i] = frag_read(bA, (wm * 64 + i * 16 + col) * BK + swr);
      bh[i] = frag_read(bB, (wn * 64 + i * 16 + col) * BK + swr);
    }
#pragma unroll
    for (int i = 0; i < 4; ++i)
#pragma unroll
      for (int j = 0; j < 4; ++j)
        acc[i][j] = mfma16(ah[i], bh[j], acc[i][j]);

    if ((s & 15) == 15) {          // ct boundary: fold acc into top2, reset
      const int cbase = chunk * CHUNKN + (s >> 4) * TN;
      int nj[4];
#pragma unroll
      for (int j = 0; j < 4; ++j) nj[j] = cbase + wn * 64 + j * 16 + col;
#pragma unroll
      for (int i = 0; i < 4; ++i)
#pragma unroll
        for (int r = 0; r < 4; ++r) {
          const int sv = i * 4 + r;
#pragma unroll
          for (int j = 0; j < 4; ++j) {
            float v = acc[i][j][r];
            float mn = fminf(v, tv1[sv]);
            bool gt = v > tv1[sv];
            tv1[sv] = gt ? v : tv1[sv];
            ti1[sv] = gt ? nj[j] : ti1[sv];
            tv2[sv] = fmaxf(tv2[sv], mn);
          }
        }
#pragma unroll
      for (int i = 0; i < 4; ++i)
#pragma unroll
        for (int j = 0; j < 4; ++j) acc[i][j] = z4;
    }

    if (s + 2 < NS1)
      asm volatile("s_waitcnt vmcnt(4)" ::: "memory");  // s+1 landed; s+2 in flight
    else
      asm volatile("s_waitcnt vmcnt(0)" ::: "memory");  // epilogue drain
    __builtin_amdgcn_s_barrier();
    __builtin_amdgcn_sched_barrier(0);
  }

  // intra-wave top-2 reduce across the 16 col-lanes (lane bits 0..3)
#pragma unroll
  for (int off = 1; off < 16; off <<= 1) {
#pragma unroll
    for (int s = 0; s < 16; ++s) {
      float ov1 = __shfl_xor(tv1[s], off, 64);
      int   oi1 = __shfl_xor(ti1[s], off, 64);
      float ov2 = __shfl_xor(tv2[s], off, 64);
      float nv2 = fmaxf(fminf(tv1[s], ov1), fmaxf(tv2[s], ov2));
      if (ov1 > tv1[s] || (ov1 == tv1[s] && oi1 < ti1[s])) { tv1[s] = ov1; ti1[s] = oi1; }
      tv2[s] = nv2;
    }
  }
  __syncthreads();   // staging LDS reuse as reduction scratch
  if (col == 0) {
#pragma unroll
    for (int s = 0; s < 16; ++s) {
      const int rl = wm * 64 + (s >> 2) * 16 + quad * 4 + (s & 3);
      u.red.v1[rl][wn] = tv1[s];
      u.red.v2[rl][wn] = tv2[s];
      u.red.i1[rl][wn] = ti1[s];
    }
  }
  __syncthreads();
  if (t < TM) {
    float V1 = u.red.v1[t][0], V2 = u.red.v2[t][0];
    int   I1 = u.red.i1[t][0];
    float a1 = u.red.v1[t][1], a2 = u.red.v2[t][1];
    int   ai = u.red.i1[t][1];
    float nv2 = fmaxf(fminf(V1, a1), fmaxf(V2, a2));
    if (a1 > V1 || (a1 == V1 && ai < I1)) { V1 = a1; I1 = ai; }
    V2 = nv2;
    const size_t o = (size_t)chunk * BROWS + row0 + t;
    pv1[o] = V1; pi1[o] = I1; pv2[o] = V2;
  }
}

// combine stage-1 partials; rows with top1-top2 gap < MARGIN1 go to flaglist.
__global__ __launch_bounds__(256) void combine1_kernel(
    const float* __restrict__ pv1, const int* __restrict__ pi1,
    const float* __restrict__ pv2, int* __restrict__ idxs,
    int* __restrict__ flagcnt, int* __restrict__ flaglist) {
  const int row = blockIdx.x * 256 + threadIdx.x;
  float V1 = pv1[row], V2 = pv2[row];
  int I1 = pi1[row];
#pragma unroll
  for (int c2 = 1; c2 < NCHUNK; ++c2) {
    const size_t o = (size_t)c2 * BROWS + row;
    float a1 = pv1[o], a2 = pv2[o];
    int ai = pi1[o];
    float nv2 = fmaxf(fminf(V1, a1), fmaxf(V2, a2));
    if (a1 > V1) { V1 = a1; I1 = ai; }
    V2 = nv2;
  }
  idxs[row] = I1;
  if (V1 - V2 < MARGIN1) {
    int p = atomicAdd(flagcnt, 1);
    flaglist[p] = row;
  }
}

// Compact flagged rows' zh/zl into contiguous buffers (in the out_q region,
// dead until finalize). One wave per slot; 1KB row = 64 lanes x 16B.
__global__ __launch_bounds__(256) void compact_kernel(
    const ushort_t* __restrict__ zh, const ushort_t* __restrict__ zl,
    const int* __restrict__ flagcnt, const int* __restrict__ flaglist,
    ushort_t* __restrict__ zhc, ushort_t* __restrict__ zlc) {
  int nf = *flagcnt;
  if (nf > NF_CAP) nf = NF_CAP;
  const int w = threadIdx.x >> 6, lane = threadIdx.x & 63;
  const int slot = blockIdx.x * 4 + w;
  if (slot >= nf) return;
  const int row = flaglist[slot];
  const float4* sh = (const float4*)(zh + (size_t)row * DDIM);
  const float4* sl = (const float4*)(zl + (size_t)row * DDIM);
  float4* dh = (float4*)(zhc + (size_t)slot * DDIM);
  float4* dl = (float4*)(zlc + (size_t)slot * DDIM);
  dh[lane] = sh[lane];
  dl[lane] = sl[lane];
}

// ---------------- stage 2: bf16x2 (3-MFMA) GEMM on compacted rows ----------
__global__ __launch_bounds__(256, 2) void gemm3f_kernel(
    const ushort_t* __restrict__ zhc, const ushort_t* __restrict__ zlc,
    const ushort_t* __restrict__ eh, const ushort_t* __restrict__ el,
    const int* __restrict__ flagcnt,
    float* __restrict__ qv1, int* __restrict__ qi1, float* __restrict__ qv2) {
  __shared__ union {
    ushort_t stg[2][4][TM * BK];                         // 64 KB
    struct { float v1[TM][2]; float v2[TM][2]; int i1[TM][2]; } red;
  } u;
  int nf = *flagcnt;
  if (nf > NF_CAP) nf = NF_CAP;
  const int row0 = blockIdx.y * TM;
  if (row0 >= nf) return;

  const int t = threadIdx.x;
  const int w = t >> 6;
  const int lane = t & 63;
  const int wm = w >> 1, wn = w & 1;
  const int col = lane & 15;
  const int quad = lane >> 4;
  const int chunk = blockIdx.x;

  const int swc = ((lane & 3) ^ ((lane >> 3) & 3)) * 8;
  const ushort_t* eb = (w == 2) ? eh : el;
  const ushort_t* ab = (w == 0) ? zhc : zlc;
  const ushort_t* gsrcA = ab + (size_t)(row0 + (lane >> 2)) * DDIM + swc;

  const int swr = (quad ^ ((col >> 1) & 3)) * 8;

  float tv1[16], tv2[16]; int ti1[16];
#pragma unroll
  for (int s = 0; s < 16; ++s) { tv1[s] = -3.0e38f; tv2[s] = -3.0e38f; ti1[s] = 0; }

  const int cbase = chunk * CHUNK2;
  const ushort_t* gsrc = (w < 2) ? gsrcA
      : eb + (size_t)(cbase + (lane >> 2)) * DDIM + swc;

  floatx4 acc[4][4];
  const floatx4 z4 = {0.f, 0.f, 0.f, 0.f};
#pragma unroll
  for (int i = 0; i < 4; ++i)
#pragma unroll
    for (int j = 0; j < 4; ++j) acc[i][j] = z4;

  {
    ushort_t* l0 = u.stg[0][w];
#pragma unroll
    for (int i = 0; i < 8; ++i)
      ld2lds16(gsrc + (size_t)(i * 16) * DDIM, l0 + i * 512);
  }
  __syncthreads();

  for (int kt = 0; kt < NKT; ++kt) {
    const int cur = kt & 1;
    if (kt + 1 < NKT) {
      ushort_t* ln = u.stg[cur ^ 1][w];
      const ushort_t* gn = gsrc + (kt + 1) * BK;
#pragma unroll
      for (int i = 0; i < 8; ++i)
        ld2lds16(gn + (size_t)(i * 16) * DDIM, ln + i * 512);
    }

    short8 ah[4], al[4], bh[4], bl[4];
#pragma unroll
    for (int i = 0; i < 4; ++i) {
      const int offA = (wm * 64 + i * 16 + col) * BK + swr;
      const int offB = (wn * 64 + i * 16 + col) * BK + swr;
      ah[i] = frag_read(u.stg[cur][0], offA);
      al[i] = frag_read(u.stg[cur][1], offA);
      bh[i] = frag_read(u.stg[cur][2], offB);
      bl[i] = frag_read(u.stg[cur][3], offB);
    }
#pragma unroll
    for (int i = 0; i < 4; ++i)
#pragma unroll
      for (int j = 0; j < 4; ++j) {
        acc[i][j] = mfma16(ah[i], bh[j], acc[i][j]);
        acc[i][j] = mfma16(ah[i], bl[j], acc[i][j]);
        acc[i][j] = mfma16(al[i], bh[j], acc[i][j]);
      }
    __syncthreads();
  }

  int nj[4];
#pragma unroll
  for (int j = 0; j < 4; ++j) nj[j] = cbase + wn * 64 + j * 16 + col;
#pragma unroll
  for (int i = 0; i < 4; ++i)
#pragma unroll
    for (int r = 0; r < 4; ++r) {
      const int s = i * 4 + r;
#pragma unroll
      for (int j = 0; j < 4; ++j) {
        float v = acc[i][j][r];
        float mn = fminf(v, tv1[s]);
        bool gt = v > tv1[s];
        tv1[s] = gt ? v : tv1[s];
        ti1[s] = gt ? nj[j] : ti1[s];
        tv2[s] = fmaxf(tv2[s], mn);
      }
    }

#pragma unroll
  for (int off = 1; off < 16; off <<= 1) {
#pragma unroll
    for (int s = 0; s < 16; ++s) {
      float ov1 = __shfl_xor(tv1[s], off, 64);
      int   oi1 = __shfl_xor(ti1[s], off, 64);
      float ov2 = __shfl_xor(tv2[s], off, 64);
      float nv2 = fmaxf(fminf(tv1[s], ov1), fmaxf(tv2[s], ov2));
      if (ov1 > tv1[s] || (ov1 == tv1[s] && oi1 < ti1[s])) { tv1[s] = ov1; ti1[s] = oi1; }
      tv2[s] = nv2;
    }
  }
  __syncthreads();
  if (col == 0) {
#pragma unroll
    for (int s = 0; s < 16; ++s) {
      const int rl = wm * 64 + (s >> 2) * 16 + quad * 4 + (s & 3);
      u.red.v1[rl][wn] = tv1[s];
      u.red.v2[rl][wn] = tv2[s];
      u.red.i1[rl][wn] = ti1[s];
    }
  }
  __syncthreads();
  if (t < TM) {
    float V1 = u.red.v1[t][0], V2 = u.red.v2[t][0];
    int   I1 = u.red.i1[t][0];
    float a1 = u.red.v1[t][1], a2 = u.red.v2[t][1];
    int   ai = u.red.i1[t][1];
    float nv2 = fmaxf(fminf(V1, a1), fmaxf(V2, a2));
    if (a1 > V1 || (a1 == V1 && ai < I1)) { V1 = a1; I1 = ai; }
    V2 = nv2;
    const size_t o = (size_t)chunk * NF_CAP + row0 + t;   // slot-indexed
    qv1[o] = V1; qi1[o] = I1; qv2[o] = V2;
  }
}

// combine stage-2 partials (slot-indexed, NSPLIT2 splits); gap < MARGIN -> rerank.
__global__ __launch_bounds__(256) void combine2_kernel(
    const float* __restrict__ qv1, const int* __restrict__ qi1,
    const float* __restrict__ qv2, const int* __restrict__ flagcnt,
    const int* __restrict__ flaglist, int* __restrict__ idxs,
    int* __restrict__ flag2cnt, int* __restrict__ flag2list) {
  int nf = *flagcnt;
  if (nf > NF_CAP) nf = NF_CAP;
  const int f = blockIdx.x * 256 + threadIdx.x;
  if (f >= nf) return;
  float V1 = qv1[f], V2 = qv2[f];
  int I1 = qi1[f];
  for (int c2 = 1; c2 < NSPLIT2; ++c2) {
    const size_t o = (size_t)c2 * NF_CAP + f;
    float a1 = qv1[o], a2 = qv2[o];
    int ai = qi1[o];
    float nv2 = fmaxf(fminf(V1, a1), fmaxf(V2, a2));
    if (a1 > V1) { V1 = a1; I1 = ai; }   // ascending chunks: tie keeps lower index
    V2 = nv2;
  }
  const int row = flaglist[f];
  idxs[row] = I1;
  if (V1 - V2 < MARGIN) {
    int p = atomicAdd(flag2cnt, 1);
    flag2list[p] = row;
  }
}

// Exact fp32 rerank, slab-parallel: task = (flagged row, 256-code slab).
__global__ __launch_bounds__(256) void rerank_kernel(
    const float* __restrict__ z, const float* __restrict__ en,
    const int* __restrict__ flagcnt, const int* __restrict__ flaglist,
    ull_t* __restrict__ pk) {
  __shared__ float sZ[512];
  __shared__ ull_t sk[4];
  const int t = threadIdx.x;
  const int w = t >> 6, lane = t & 63;
  int nf = *flagcnt;
  if (nf > BROWS) nf = BROWS;
  const int ntask = nf * 32;
  for (int task = blockIdx.x; task < ntask; task += gridDim.x) {
    const int f = task >> 5, slab = task & 31;
    const int row = flaglist[f];
    __syncthreads();
    if (t < 128) ((float4*)sZ)[t] = ((const float4*)(z + (size_t)row * DDIM))[t];
    __syncthreads();
    const float4 za = ((const float4*)sZ)[lane];
    const float4 zb = ((const float4*)sZ)[lane + 64];
    const int c0 = slab * 256 + w * 64;
    ull_t bk = 0;
    for (int cc = 0; cc < 64; ++cc) {
      const int c = c0 + cc;
      const float4* ep = (const float4*)(en + (size_t)c * DDIM);
      float4 ea = ep[lane], eb = ep[lane + 64];
      float d = ea.x*za.x + ea.y*za.y + ea.z*za.z + ea.w*za.w
              + eb.x*zb.x + eb.y*zb.y + eb.z*zb.z + eb.w*zb.w;
      d = wave_sum(d);
      ull_t k2 = pack_key(d, c);
      if (k2 > bk) bk = k2;
    }
    if (lane == 0) sk[w] = bk;
    __syncthreads();
    if (t == 0) {
      ull_t m = sk[0];
      if (sk[1] > m) m = sk[1];
      if (sk[2] > m) m = sk[2];
      if (sk[3] > m) m = sk[3];
      atomicMax(&pk[f], m);
    }
  }
}

__global__ __launch_bounds__(256) void unpack_kernel(
    const int* __restrict__ flagcnt, const int* __restrict__ flaglist,
    const ull_t* __restrict__ pk, int* __restrict__ idxs) {
  int nf = *flagcnt;
  if (nf > BROWS) nf = BROWS;
  for (int f = blockIdx.x * 256 + threadIdx.x; f < nf; f += gridDim.x * 256)
    idxs[flaglist[f]] = (NCODES - 1) - (int)(pk[f] & 0xFFFFFFFFu);
}

// finalize: per-block loss partial (no same-address global atomics).
__global__ __launch_bounds__(256) void finalize_kernel(const float* __restrict__ z,
                                                       const float* __restrict__ en,
                                                       const int* __restrict__ idxs,
                                                       float* __restrict__ out_q,
                                                       float* __restrict__ out_i,
                                                       float* __restrict__ counts,
                                                       float* __restrict__ lossp) {
  __shared__ float sdl[4];
  int w = threadIdx.x >> 6, lane = threadIdx.x & 63;
  int row = blockIdx.x * 4 + w;
  const float4* zr = (const float4*)(z + (size_t)row * DDIM);
  float4 a = zr[lane], b = zr[lane + 64];
  float s = a.x*a.x + a.y*a.y + a.z*a.z + a.w*a.w
          + b.x*b.x + b.y*b.y + b.z*b.z + b.w*b.w;
  s = wave_sum(s);
  float inv = 1.0f / fmaxf(sqrtf(s), 1e-12f);
  int k = idxs[row];
  const float4* qr = (const float4*)(en + (size_t)k * DDIM);
  float4 qa = qr[lane], qb = qr[lane + 64];
  float d = 0.0f;
  float4 oa, ob;
  {
    float zn;
    zn = a.x * inv; oa.x = zn + (qa.x - zn); d += (zn - qa.x) * (zn - qa.x);
    zn = a.y * inv; oa.y = zn + (qa.y - zn); d += (zn - qa.y) * (zn - qa.y);
    zn = a.z * inv; oa.z = zn + (qa.z - zn); d += (zn - qa.z) * (zn - qa.z);
    zn = a.w * inv; oa.w = zn + (qa.w - zn); d += (zn - qa.w) * (zn - qa.w);
    zn = b.x * inv; ob.x = zn + (qb.x - zn); d += (zn - qb.x) * (zn - qb.x);
    zn = b.y * inv; ob.y = zn + (qb.y - zn); d += (zn - qb.y) * (zn - qb.y);
    zn = b.z * inv; ob.z = zn + (qb.z - zn); d += (zn - qb.z) * (zn - qb.z);
    zn = b.w * inv; ob.w = zn + (qb.w - zn); d += (zn - qb.w) * (zn - qb.w);
  }
  float4* orow = (float4*)(out_q + (size_t)row * DDIM);
  orow[lane] = oa;
  orow[lane + 64] = ob;
  d = wave_sum(d);
  if (lane == 0) {
    sdl[w] = d;
    atomicAdd(&counts[k], 1.0f);
    out_i[row] = (float)k;
  }
  __syncthreads();
  if (threadIdx.x == 0)
    lossp[blockIdx.x] = sdl[0] + sdl[1] + sdl[2] + sdl[3];
}

__global__ __launch_bounds__(256) void scalars_kernel(const float* __restrict__ counts,
                                                      const float* __restrict__ lossp,
                                                      float* __restrict__ o) {
  __shared__ float se[256], su[256], sl[256];
  int t = threadIdx.x;
  float ent = 0.0f, utl = 0.0f, lsum = 0.0f;
  for (int i = t; i < NCODES; i += 256) {
    float c = counts[i];
    float p = c * (1.0f / (float)BROWS);
    ent -= p * logf(p + 1e-10f);
    utl += (c > 0.0f) ? 1.0f : 0.0f;
    lsum += lossp[i];
  }
  se[t] = ent; su[t] = utl; sl[t] = lsum;
  __syncthreads();
  for (int s2 = 128; s2 > 0; s2 >>= 1) {
    if (t < s2) { se[t] += se[t + s2]; su[t] += su[t + s2]; sl[t] += sl[t + s2]; }
    __syncthreads();
  }
  if (t == 0) {
    float mse = sl[0] * (1.0f / (float)(BROWS * DDIM));
    o[0] = 0.25f * mse;
    o[1] = mse;
    o[2] = expf(se[0]);
    o[3] = su[0] * (1.0f / (float)NCODES);
  }
}

// ---------- fallback (fp32 path, used only if ws too small) ----------
__global__ __launch_bounds__(256) void fb_norm_rows(const float* __restrict__ e,
                                                    float* __restrict__ en) {
  int w = threadIdx.x >> 6, lane = threadIdx.x & 63;
  int row = blockIdx.x * 4 + w;
  const float4* src = (const float4*)(e + (size_t)row * DDIM);
  float4 a = src[lane], b = src[lane + 64];
  float s = a.x*a.x + a.y*a.y + a.z*a.z + a.w*a.w
          + b.x*b.x + b.y*b.y + b.z*b.z + b.w*b.w;
  s = wave_sum(s);
  float inv = 1.0f / fmaxf(sqrtf(s), 1e-12f);
  float4* dst = (float4*)(en + (size_t)row * DDIM);
  dst[lane] = make_float4(a.x*inv, a.y*inv, a.z*inv, a.w*inv);
  dst[lane + 64] = make_float4(b.x*inv, b.y*inv, b.z*inv, b.w*inv);
}

__global__ __launch_bounds__(256) void fb_gemm_argmax(const float* __restrict__ z,
                                                      const float* __restrict__ en,
                                                      int* __restrict__ out_idx) {
  __shared__ float As[16][TM + 4];
  __shared__ float Bs[16][TN + 4];
  __shared__ float rv[TM][16];
  __shared__ int   ri[TM][16];
  const int t = threadIdx.x;
  const int tx = t & 15, ty = t >> 4;
  const int row0 = blockIdx.x * TM;
  const int m = t >> 2, f4 = t & 3;
  float bestv[8]; int bestn[8];
#pragma unroll
  for (int i = 0; i < 8; ++i) { bestv[i] = -3.0e38f; bestn[i] = 0; }
  for (int ct = 0; ct < NCODES / TN; ++ct) {
    float acc[8][8];
#pragma unroll
    for (int i = 0; i < 8; ++i)
#pragma unroll
      for (int j = 0; j < 8; ++j) acc[i][j] = 0.0f;
    for (int kt = 0; kt < DDIM / 16; ++kt) {
      const int k0 = kt * 16;
      __syncthreads();
      {
        const float* zb = z + (size_t)(row0 + m) * DDIM + k0 + f4 * 4;
        float4 v0 = *(const float4*)zb;
        float4 v1 = *(const float4*)(zb + (size_t)64 * DDIM);
        const float* ebp = en + (size_t)(ct * TN + m) * DDIM + k0 + f4 * 4;
        float4 w0 = *(const float4*)ebp;
        float4 w1 = *(const float4*)(ebp + (size_t)64 * DDIM);
        const int kk = f4 * 4;
        As[kk+0][m] = v0.x; As[kk+1][m] = v0.y; As[kk+2][m] = v0.z; As[kk+3][m] = v0.w;
        As[kk+0][m+64] = v1.x; As[kk+1][m+64] = v1.y; As[kk+2][m+64] = v1.z; As[kk+3][m+64] = v1.w;
        Bs[kk+0][m] = w0.x; Bs[kk+1][m] = w0.y; Bs[kk+2][m] = w0.z; Bs[kk+3][m] = w0.w;
        Bs[kk+0][m+64] = w1.x; Bs[kk+1][m+64] = w1.y; Bs[kk+2][m+64] = w1.z; Bs[kk+3][m+64] = w1.w;
      }
      __syncthreads();
#pragma unroll
      for (int k = 0; k < 16; ++k) {
        float4 a0 = *(const float4*)&As[k][ty * 8];
        float4 a1 = *(const float4*)&As[k][ty * 8 + 4];
        float4 b0 = *(const float4*)&Bs[k][tx * 4];
        float4 b1 = *(const float4*)&Bs[k][64 + tx * 4];
        float a[8] = {a0.x,a0.y,a0.z,a0.w,a1.x,a1.y,a1.z,a1.w};
        float b[8] = {b0.x,b0.y,b0.z,b0.w,b1.x,b1.y,b1.z,b1.w};
#pragma unroll
        for (int i = 0; i < 8; ++i)
#pragma unroll
          for (int j = 0; j < 8; ++j) acc[i][j] = fmaf(a[i], b[j], acc[i][j]);
      }
    }
    const int nb = ct * TN;
#pragma unroll
    for (int i = 0; i < 8; ++i)
#pragma unroll
      for (int j = 0; j < 8; ++j) {
        int n = nb + ((j < 4) ? (tx * 4 + j) : (64 + tx * 4 + (j - 4)));
        if (acc[i][j] > bestv[i]) { bestv[i] = acc[i][j]; bestn[i] = n; }
      }
  }
#pragma unroll
  for (int i = 0; i < 8; ++i) { rv[ty*8+i][tx] = bestv[i]; ri[ty*8+i][tx] = bestn[i]; }
  __syncthreads();
  if (t < TM) {
    float bv = rv[t][0]; int bi = ri[t][0];
#pragma unroll
    for (int x = 1; x < 16; ++x) {
      float v = rv[t][x]; int n = ri[t][x];
      if (v > bv || (v == bv && n < bi)) { bv = v; bi = n; }
    }
    out_idx[row0 + t] = bi;
  }
}

extern "C" void kernel_launch(void* const* d_in, const int* in_sizes, int n_in,
                              void* d_out, int out_size, void* d_ws, size_t ws_size,
                              hipStream_t stream) {
  const float* z = (const float*)d_in[0];
  const float* e = (const float*)d_in[1];
  float* out = (float*)d_out;
  float* ws = (float*)d_ws;

  float* out_q = out;
  float* out_i = out + (size_t)BROWS * DDIM;
  float* out_s = out_i + BROWS;

  const size_t ENF = (size_t)NCODES * DDIM;   // 4,194,304
  const size_t ZNF = (size_t)BROWS * DDIM;    // 16,777,216
  const size_t NFIN = BROWS / 4;              // 8192 finalize blocks

  // stage-2 compact buffers live in out_q (67 MB, dead until finalize).
  ushort_t* zhc = (ushort_t*)out_q;
  ushort_t* zlc = zhc + (size_t)NF_CAP * DDIM;

  // fast-path ws layout (float-unit offsets)
  size_t off = 0;
  float*    en       = ws + off;              off += ENF;
  ushort_t* enh      = (ushort_t*)(ws + off); off += ENF / 2;
  ushort_t* enl      = (ushort_t*)(ws + off); off += ENF / 2;
  ushort_t* zh       = (ushort_t*)(ws + off); off += ZNF / 2;
  ushort_t* zl       = (ushort_t*)(ws + off); off += ZNF / 2;
  float*    pv1      = ws + off;              off += (size_t)NCHUNK * BROWS;
  int*      pi1      = (int*)(ws + off);      off += (size_t)NCHUNK * BROWS;
  float*    pv2      = ws + off;              off += (size_t)NCHUNK * BROWS;
  float*    qv1      = ws + off;              off += (size_t)NSPLIT2 * NF_CAP;
  int*      qi1      = (int*)(ws + off);      off += (size_t)NSPLIT2 * NF_CAP;
  float*    qv2      = ws + off;              off += (size_t)NSPLIT2 * NF_CAP;
  int*      idxs     = (int*)(ws + off);      off += BROWS;
  int*      flaglist = (int*)(ws + off);      off += BROWS;
  int*      flag2list= (int*)(ws + off);      off += BROWS;
  float*    lossp    = ws + off;              off += NFIN;
  // zeroed region: counts | flagcnt | flag2cnt | pad | pk  (single memset)
  float*    counts   = ws + off;              off += NCODES;
  int*      flagcnt  = (int*)(ws + off);      off += 1;
  int*      flag2cnt = (int*)(ws + off);      off += 1;
  if (off & 1) off += 1;                      // 8B-align pk
  ull_t*    pk       = (ull_t*)(ws + off);    off += (size_t)BROWS * 2;
  const size_t need_bytes = off * sizeof(float);
  const size_t zero_bytes = (size_t)((char*)(pk + BROWS) - (char*)counts);

  if (ws_size >= need_bytes) {
    prep_split_kernel<<<NCODES / 4, 256, 0, stream>>>(e, en, enh, enl);
    prep_split_kernel<<<BROWS / 4, 256, 0, stream>>>(z, nullptr, zh, zl);
    hipMemsetAsync(counts, 0, zero_bytes, stream);
    dim3 g1(NCHUNK, BROWS / TM);
    gemm1_kernel<<<g1, 256, 0, stream>>>(zh, enh, pv1, pi1, pv2);
    combine1_kernel<<<BROWS / 256, 256, 0, stream>>>(pv1, pi1, pv2, idxs, flagcnt, flaglist);
    compact_kernel<<<NF_CAP / 4, 256, 0, stream>>>(zh, zl, flagcnt, flaglist, zhc, zlc);
    dim3 g2(NSPLIT2, NF_CAP / TM);
    gemm3f_kernel<<<g2, 256, 0, stream>>>(zhc, zlc, enh, enl, flagcnt, qv1, qi1, qv2);
    combine2_kernel<<<NF_CAP / 256, 256, 0, stream>>>(qv1, qi1, qv2, flagcnt, flaglist,
                                                      idxs, flag2cnt, flag2list);
    rerank_kernel<<<1024, 256, 0, stream>>>(z, en, flag2cnt, flag2list, pk);
    unpack_kernel<<<32, 256, 0, stream>>>(flag2cnt, flag2list, pk, idxs);
    finalize_kernel<<<BROWS / 4, 256, 0, stream>>>(z, en, idxs, out_q, out_i, counts, lossp);
    scalars_kernel<<<1, 256, 0, stream>>>(counts, lossp, out_s);
  } else {
    // fallback: fp32 path (~17 MB ws)
    float* fen    = ws;
    int*   fidx   = (int*)(fen + ENF);
    float* fcnt   = (float*)(fidx + BROWS);
    float* flossp = fcnt + NCODES;
    fb_norm_rows<<<NCODES / 4, 256, 0, stream>>>(e, fen);
    hipMemsetAsync(fcnt, 0, NCODES * sizeof(float), stream);
    fb_gemm_argmax<<<BROWS / TM, 256, 0, stream>>>(z, fen, fidx);
    finalize_kernel<<<BROWS / 4, 256, 0, stream>>>(z, fen, fidx, out_q, out_i, fcnt, flossp);
    scalars_kernel<<<1, 256, 0, stream>>>(fcnt, flossp, out_s);
  }
}

// Round 11
// 614.125 us; speedup vs baseline: 1.2433x; 1.2433x over previous
//
#include <hip/hip_runtime.h>

#define BROWS  32768
#define DDIM   512
#define NCODES 8192
#define NCHUNK 4
#define CHUNKN (NCODES / NCHUNK)   // 2048
#define NSPLIT2 64                 // stage-2 N-splits
#define CHUNK2 (NCODES / NSPLIT2)  // 128
#define NF_CAP 8192                // stage-2 row-slot capacity (nf expected ~1900)
#define TM     128
#define TN     128
#define BK     32
#define NKT    (DDIM / BK)         // 16
#define MARGIN1 6.0e-4f            // stage-1 (hh-only) pair-error bound, ~6 sigma
#define MARGIN  6e-6f              // stage-2 (bf16x2 3-MFMA) error bound

typedef unsigned short ushort_t;
typedef unsigned int   uint_t;
typedef unsigned long long ull_t;
typedef __attribute__((ext_vector_type(8))) short  short8;
typedef __attribute__((ext_vector_type(4))) float  floatx4;

__device__ __forceinline__ float wave_sum(float v) {
#pragma unroll
  for (int o = 32; o > 0; o >>= 1) v += __shfl_xor(v, o, 64);
  return v;
}

__device__ __forceinline__ floatx4 mfma16(short8 a, short8 b, floatx4 c) {
  return __builtin_amdgcn_mfma_f32_16x16x32_bf16(a, b, c, 0, 0, 0);
}

// async global->LDS, 16B per lane; lds dst is wave-uniform base + lane*16 (HW rule)
__device__ __forceinline__ void ld2lds16(const ushort_t* g, ushort_t* l) {
  __builtin_amdgcn_global_load_lds((__attribute__((address_space(1))) void*)g,
                                   (__attribute__((address_space(3))) void*)l,
                                   16, 0, 0);
}

__device__ __forceinline__ void split1(float v, ushort_t& h, ushort_t& l) {
  uint_t u  = __float_as_uint(v);
  uint_t hb = (u + 0x7FFFu + ((u >> 16) & 1u)) >> 16;   // RNE
  h = (ushort_t)hb;
  float r = v - __uint_as_float(hb << 16);               // exact (Sterbenz)
  uint_t u2 = __float_as_uint(r);
  l = (ushort_t)((u2 + 0x7FFFu + ((u2 >> 16) & 1u)) >> 16);
}

// ordered-uint pack: key orders by value, then by LOWER index (tie-break)
__device__ __forceinline__ ull_t pack_key(float v, int c) {
  uint_t u = __float_as_uint(v);
  u = (u & 0x80000000u) ? ~u : (u | 0x80000000u);
  return ((ull_t)u << 32) | (uint_t)(NCODES - 1 - c);
}

// Normalize rows of x (4 rows/block, wave per row); write fp32 (optional) + bf16 hi/lo.
__global__ __launch_bounds__(256) void prep_split_kernel(const float* __restrict__ x,
                                                         float* __restrict__ xn,
                                                         ushort_t* __restrict__ xh,
                                                         ushort_t* __restrict__ xl) {
  const int w = threadIdx.x >> 6, lane = threadIdx.x & 63;
  const size_t row = (size_t)blockIdx.x * 4 + w;
  const float4* src = (const float4*)(x + row * DDIM);
  float4 a = src[lane], b = src[lane + 64];
  float s = a.x*a.x + a.y*a.y + a.z*a.z + a.w*a.w
          + b.x*b.x + b.y*b.y + b.z*b.z + b.w*b.w;
  s = wave_sum(s);
  const float inv = 1.0f / fmaxf(sqrtf(s), 1e-12f);
  a.x *= inv; a.y *= inv; a.z *= inv; a.w *= inv;
  b.x *= inv; b.y *= inv; b.z *= inv; b.w *= inv;
  if (xn) {
    float4* dst = (float4*)(xn + row * DDIM);
    dst[lane] = a; dst[lane + 64] = b;
  }
  ushort4 h0, l0, h1, l1;
  split1(a.x, h0.x, l0.x); split1(a.y, h0.y, l0.y);
  split1(a.z, h0.z, l0.z); split1(a.w, h0.w, l0.w);
  split1(b.x, h1.x, l1.x); split1(b.y, h1.y, l1.y);
  split1(b.z, h1.z, l1.z); split1(b.w, h1.w, l1.w);
  ushort4* ph = (ushort4*)(xh + row * DDIM);
  ushort4* pl = (ushort4*)(xl + row * DDIM);
  ph[lane] = h0; ph[lane + 64] = h1;
  pl[lane] = l0; pl[lane + 64] = l1;
}

// Fragment read: single ds_read_b128 at the XOR-swizzled 16B chunk position.
__device__ __forceinline__ short8 frag_read(const ushort_t* base, int off16) {
  return *(const short8*)(base + off16);
}

// ---------------- stage 1: hh-only (1-MFMA) screening GEMM ----------------
// R8 post-mortem: counted-vmcnt 3-deep pipeline spilled (WRITE_SIZE 25->247MB,
// 400->500us) — second failed pipelining attempt; axis abandoned. Instead,
// amortize the per-barrier drain: TWO BK=32 sub-tiles per barrier (paired kt).
// Each sub keeps the exact verified BK=32 swizzle/layout. Barriers/ct: 32->16,
// 32 MFMA per drain instead of 16. LDS 64KB; still 2 blocks/CU (VGPR-bound).
// (256,2): R4 measured (256,3) spills. Keep 2.
__global__ __launch_bounds__(256, 2) void gemm1_kernel(
    const ushort_t* __restrict__ zh, const ushort_t* __restrict__ eh,
    float* __restrict__ pv1, int* __restrict__ pi1, float* __restrict__ pv2) {
  __shared__ union {
    ushort_t stg[2][2][2][TM * BK];   // [buf][mat][sub][4096] = 64 KB
    struct { float v1[TM][2]; float v2[TM][2]; int i1[TM][2]; } red;  // 3 KB
  } u;
  const int t = threadIdx.x;
  const int w = t >> 6;            // wave 0..3
  const int lane = t & 63;
  const int wm = w >> 1, wn = w & 1;
  const int col = lane & 15;
  const int quad = lane >> 4;
  const int chunk = blockIdx.x;
  const int row0 = blockIdx.y * TM;

  // staging: lane l -> row (l>>2), swizzled chunk (l&3)^((l>>3)&3)
  const int swc = ((lane & 3) ^ ((lane >> 3) & 3)) * 8;
  const int matsel = w >> 1;       // 0: stage Ah, 1: stage Bh
  const int half = w & 1;          // row-half 0..63 / 64..127
  const ushort_t* gsrcA = zh + (size_t)(row0 + half * 64 + (lane >> 2)) * DDIM + swc;

  // fragment-read swizzle: 16B chunk (quad ^ ((col>>1)&3))
  const int swr = (quad ^ ((col >> 1) & 3)) * 8;

  float tv1[16], tv2[16]; int ti1[16];
#pragma unroll
  for (int s = 0; s < 16; ++s) { tv1[s] = -3.0e38f; tv2[s] = -3.0e38f; ti1[s] = 0; }

  for (int ct = 0; ct < CHUNKN / TN; ++ct) {
    const int cbase = chunk * CHUNKN + ct * TN;
    const ushort_t* gsrc = (matsel == 0) ? gsrcA
        : eh + (size_t)(cbase + half * 64 + (lane >> 2)) * DDIM + swc;

    floatx4 acc[4][4];
    const floatx4 z4 = {0.f, 0.f, 0.f, 0.f};
#pragma unroll
    for (int i = 0; i < 4; ++i)
#pragma unroll
      for (int j = 0; j < 4; ++j) acc[i][j] = z4;

    // prologue: stage kt=0 (sub 0) and kt=1 (sub 1) into buf 0
    {
      ushort_t* l0 = u.stg[0][matsel][0] + half * 2048;
      ushort_t* l1 = u.stg[0][matsel][1] + half * 2048;
#pragma unroll
      for (int i = 0; i < 4; ++i) {
        ld2lds16(gsrc + (size_t)(i * 16) * DDIM,      l0 + i * 512);
        ld2lds16(gsrc + (size_t)(i * 16) * DDIM + BK, l1 + i * 512);
      }
    }
    __syncthreads();

    for (int p = 0; p < NKT / 2; ++p) {      // 8 double-steps
      const int cur = p & 1;
      if (p + 1 < NKT / 2) {                 // stage kts 2p+2, 2p+3
        ushort_t* l0 = u.stg[cur ^ 1][matsel][0] + half * 2048;
        ushort_t* l1 = u.stg[cur ^ 1][matsel][1] + half * 2048;
        const ushort_t* g = gsrc + (p + 1) * (2 * BK);
#pragma unroll
        for (int i = 0; i < 4; ++i) {
          ld2lds16(g + (size_t)(i * 16) * DDIM,      l0 + i * 512);
          ld2lds16(g + (size_t)(i * 16) * DDIM + BK, l1 + i * 512);
        }
      }

#pragma unroll
      for (int sub = 0; sub < 2; ++sub) {
        short8 ah[4], bh[4];
#pragma unroll
        for (int i = 0; i < 4; ++i) {
          ah[i] = frag_read(u.stg[cur][0][sub], (wm * 64 + i * 16 + col) * BK + swr);
          bh[i] = frag_read(u.stg[cur][1][sub], (wn * 64 + i * 16 + col) * BK + swr);
        }
#pragma unroll
        for (int i = 0; i < 4; ++i)
#pragma unroll
          for (int j = 0; j < 4; ++j)
            acc[i][j] = mfma16(ah[i], bh[j], acc[i][j]);
      }
      __syncthreads();   // drains next-buf loads; cur buf safe to overwrite
    }

    int nj[4];
#pragma unroll
    for (int j = 0; j < 4; ++j) nj[j] = cbase + wn * 64 + j * 16 + col;
#pragma unroll
    for (int i = 0; i < 4; ++i)
#pragma unroll
      for (int r = 0; r < 4; ++r) {
        const int s = i * 4 + r;
#pragma unroll
        for (int j = 0; j < 4; ++j) {
          float v = acc[i][j][r];
          float mn = fminf(v, tv1[s]);
          bool gt = v > tv1[s];
          tv1[s] = gt ? v : tv1[s];
          ti1[s] = gt ? nj[j] : ti1[s];
          tv2[s] = fmaxf(tv2[s], mn);
        }
      }
  }

  // intra-wave top-2 reduce across the 16 col-lanes (lane bits 0..3)
#pragma unroll
  for (int off = 1; off < 16; off <<= 1) {
#pragma unroll
    for (int s = 0; s < 16; ++s) {
      float ov1 = __shfl_xor(tv1[s], off, 64);
      int   oi1 = __shfl_xor(ti1[s], off, 64);
      float ov2 = __shfl_xor(tv2[s], off, 64);
      float nv2 = fmaxf(fminf(tv1[s], ov1), fmaxf(tv2[s], ov2));
      if (ov1 > tv1[s] || (ov1 == tv1[s] && oi1 < ti1[s])) { tv1[s] = ov1; ti1[s] = oi1; }
      tv2[s] = nv2;
    }
  }
  __syncthreads();   // staging LDS reuse as reduction scratch
  if (col == 0) {
#pragma unroll
    for (int s = 0; s < 16; ++s) {
      const int rl = wm * 64 + (s >> 2) * 16 + quad * 4 + (s & 3);
      u.red.v1[rl][wn] = tv1[s];
      u.red.v2[rl][wn] = tv2[s];
      u.red.i1[rl][wn] = ti1[s];
    }
  }
  __syncthreads();
  if (t < TM) {
    float V1 = u.red.v1[t][0], V2 = u.red.v2[t][0];
    int   I1 = u.red.i1[t][0];
    float a1 = u.red.v1[t][1], a2 = u.red.v2[t][1];
    int   ai = u.red.i1[t][1];
    float nv2 = fmaxf(fminf(V1, a1), fmaxf(V2, a2));
    if (a1 > V1 || (a1 == V1 && ai < I1)) { V1 = a1; I1 = ai; }
    V2 = nv2;
    const size_t o = (size_t)chunk * BROWS + row0 + t;
    pv1[o] = V1; pi1[o] = I1; pv2[o] = V2;
  }
}

// combine stage-1 partials; rows with top1-top2 gap < MARGIN1 go to flaglist.
__global__ __launch_bounds__(256) void combine1_kernel(
    const float* __restrict__ pv1, const int* __restrict__ pi1,
    const float* __restrict__ pv2, int* __restrict__ idxs,
    int* __restrict__ flagcnt, int* __restrict__ flaglist) {
  const int row = blockIdx.x * 256 + threadIdx.x;
  float V1 = pv1[row], V2 = pv2[row];
  int I1 = pi1[row];
#pragma unroll
  for (int c2 = 1; c2 < NCHUNK; ++c2) {
    const size_t o = (size_t)c2 * BROWS + row;
    float a1 = pv1[o], a2 = pv2[o];
    int ai = pi1[o];
    float nv2 = fmaxf(fminf(V1, a1), fmaxf(V2, a2));
    if (a1 > V1) { V1 = a1; I1 = ai; }
    V2 = nv2;
  }
  idxs[row] = I1;
  if (V1 - V2 < MARGIN1) {
    int p = atomicAdd(flagcnt, 1);
    flaglist[p] = row;
  }
}

// Compact flagged rows' zh/zl into contiguous buffers (in the out_q region,
// dead until finalize). One wave per slot; 1KB row = 64 lanes x 16B.
__global__ __launch_bounds__(256) void compact_kernel(
    const ushort_t* __restrict__ zh, const ushort_t* __restrict__ zl,
    const int* __restrict__ flagcnt, const int* __restrict__ flaglist,
    ushort_t* __restrict__ zhc, ushort_t* __restrict__ zlc) {
  int nf = *flagcnt;
  if (nf > NF_CAP) nf = NF_CAP;
  const int w = threadIdx.x >> 6, lane = threadIdx.x & 63;
  const int slot = blockIdx.x * 4 + w;
  if (slot >= nf) return;
  const int row = flaglist[slot];
  const float4* sh = (const float4*)(zh + (size_t)row * DDIM);
  const float4* sl = (const float4*)(zl + (size_t)row * DDIM);
  float4* dh = (float4*)(zhc + (size_t)slot * DDIM);
  float4* dl = (float4*)(zlc + (size_t)slot * DDIM);
  dh[lane] = sh[lane];
  dl[lane] = sl[lane];
}

// ---------------- stage 2: bf16x2 (3-MFMA) GEMM on compacted rows ----------
__global__ __launch_bounds__(256, 2) void gemm3f_kernel(
    const ushort_t* __restrict__ zhc, const ushort_t* __restrict__ zlc,
    const ushort_t* __restrict__ eh, const ushort_t* __restrict__ el,
    const int* __restrict__ flagcnt,
    float* __restrict__ qv1, int* __restrict__ qi1, float* __restrict__ qv2) {
  __shared__ union {
    ushort_t stg[2][4][TM * BK];                         // 64 KB
    struct { float v1[TM][2]; float v2[TM][2]; int i1[TM][2]; } red;
  } u;
  int nf = *flagcnt;
  if (nf > NF_CAP) nf = NF_CAP;
  const int row0 = blockIdx.y * TM;
  if (row0 >= nf) return;

  const int t = threadIdx.x;
  const int w = t >> 6;
  const int lane = t & 63;
  const int wm = w >> 1, wn = w & 1;
  const int col = lane & 15;
  const int quad = lane >> 4;
  const int chunk = blockIdx.x;

  const int swc = ((lane & 3) ^ ((lane >> 3) & 3)) * 8;
  const ushort_t* eb = (w == 2) ? eh : el;
  const ushort_t* ab = (w == 0) ? zhc : zlc;
  const ushort_t* gsrcA = ab + (size_t)(row0 + (lane >> 2)) * DDIM + swc;

  const int swr = (quad ^ ((col >> 1) & 3)) * 8;

  float tv1[16], tv2[16]; int ti1[16];
#pragma unroll
  for (int s = 0; s < 16; ++s) { tv1[s] = -3.0e38f; tv2[s] = -3.0e38f; ti1[s] = 0; }

  const int cbase = chunk * CHUNK2;
  const ushort_t* gsrc = (w < 2) ? gsrcA
      : eb + (size_t)(cbase + (lane >> 2)) * DDIM + swc;

  floatx4 acc[4][4];
  const floatx4 z4 = {0.f, 0.f, 0.f, 0.f};
#pragma unroll
  for (int i = 0; i < 4; ++i)
#pragma unroll
    for (int j = 0; j < 4; ++j) acc[i][j] = z4;

  {
    ushort_t* l0 = u.stg[0][w];
#pragma unroll
    for (int i = 0; i < 8; ++i)
      ld2lds16(gsrc + (size_t)(i * 16) * DDIM, l0 + i * 512);
  }
  __syncthreads();

  for (int kt = 0; kt < NKT; ++kt) {
    const int cur = kt & 1;
    if (kt + 1 < NKT) {
      ushort_t* ln = u.stg[cur ^ 1][w];
      const ushort_t* gn = gsrc + (kt + 1) * BK;
#pragma unroll
      for (int i = 0; i < 8; ++i)
        ld2lds16(gn + (size_t)(i * 16) * DDIM, ln + i * 512);
    }

    short8 ah[4], al[4], bh[4], bl[4];
#pragma unroll
    for (int i = 0; i < 4; ++i) {
      const int offA = (wm * 64 + i * 16 + col) * BK + swr;
      const int offB = (wn * 64 + i * 16 + col) * BK + swr;
      ah[i] = frag_read(u.stg[cur][0], offA);
      al[i] = frag_read(u.stg[cur][1], offA);
      bh[i] = frag_read(u.stg[cur][2], offB);
      bl[i] = frag_read(u.stg[cur][3], offB);
    }
#pragma unroll
    for (int i = 0; i < 4; ++i)
#pragma unroll
      for (int j = 0; j < 4; ++j) {
        acc[i][j] = mfma16(ah[i], bh[j], acc[i][j]);
        acc[i][j] = mfma16(ah[i], bl[j], acc[i][j]);
        acc[i][j] = mfma16(al[i], bh[j], acc[i][j]);
      }
    __syncthreads();
  }

  int nj[4];
#pragma unroll
  for (int j = 0; j < 4; ++j) nj[j] = cbase + wn * 64 + j * 16 + col;
#pragma unroll
  for (int i = 0; i < 4; ++i)
#pragma unroll
    for (int r = 0; r < 4; ++r) {
      const int s = i * 4 + r;
#pragma unroll
      for (int j = 0; j < 4; ++j) {
        float v = acc[i][j][r];
        float mn = fminf(v, tv1[s]);
        bool gt = v > tv1[s];
        tv1[s] = gt ? v : tv1[s];
        ti1[s] = gt ? nj[j] : ti1[s];
        tv2[s] = fmaxf(tv2[s], mn);
      }
    }

#pragma unroll
  for (int off = 1; off < 16; off <<= 1) {
#pragma unroll
    for (int s = 0; s < 16; ++s) {
      float ov1 = __shfl_xor(tv1[s], off, 64);
      int   oi1 = __shfl_xor(ti1[s], off, 64);
      float ov2 = __shfl_xor(tv2[s], off, 64);
      float nv2 = fmaxf(fminf(tv1[s], ov1), fmaxf(tv2[s], ov2));
      if (ov1 > tv1[s] || (ov1 == tv1[s] && oi1 < ti1[s])) { tv1[s] = ov1; ti1[s] = oi1; }
      tv2[s] = nv2;
    }
  }
  __syncthreads();
  if (col == 0) {
#pragma unroll
    for (int s = 0; s < 16; ++s) {
      const int rl = wm * 64 + (s >> 2) * 16 + quad * 4 + (s & 3);
      u.red.v1[rl][wn] = tv1[s];
      u.red.v2[rl][wn] = tv2[s];
      u.red.i1[rl][wn] = ti1[s];
    }
  }
  __syncthreads();
  if (t < TM) {
    float V1 = u.red.v1[t][0], V2 = u.red.v2[t][0];
    int   I1 = u.red.i1[t][0];
    float a1 = u.red.v1[t][1], a2 = u.red.v2[t][1];
    int   ai = u.red.i1[t][1];
    float nv2 = fmaxf(fminf(V1, a1), fmaxf(V2, a2));
    if (a1 > V1 || (a1 == V1 && ai < I1)) { V1 = a1; I1 = ai; }
    V2 = nv2;
    const size_t o = (size_t)chunk * NF_CAP + row0 + t;   // slot-indexed
    qv1[o] = V1; qi1[o] = I1; qv2[o] = V2;
  }
}

// combine stage-2 partials (slot-indexed, NSPLIT2 splits); gap < MARGIN -> rerank.
__global__ __launch_bounds__(256) void combine2_kernel(
    const float* __restrict__ qv1, const int* __restrict__ qi1,
    const float* __restrict__ qv2, const int* __restrict__ flagcnt,
    const int* __restrict__ flaglist, int* __restrict__ idxs,
    int* __restrict__ flag2cnt, int* __restrict__ flag2list) {
  int nf = *flagcnt;
  if (nf > NF_CAP) nf = NF_CAP;
  const int f = blockIdx.x * 256 + threadIdx.x;
  if (f >= nf) return;
  float V1 = qv1[f], V2 = qv2[f];
  int I1 = qi1[f];
  for (int c2 = 1; c2 < NSPLIT2; ++c2) {
    const size_t o = (size_t)c2 * NF_CAP + f;
    float a1 = qv1[o], a2 = qv2[o];
    int ai = qi1[o];
    float nv2 = fmaxf(fminf(V1, a1), fmaxf(V2, a2));
    if (a1 > V1) { V1 = a1; I1 = ai; }   // ascending chunks: tie keeps lower index
    V2 = nv2;
  }
  const int row = flaglist[f];
  idxs[row] = I1;
  if (V1 - V2 < MARGIN) {
    int p = atomicAdd(flag2cnt, 1);
    flag2list[p] = row;
  }
}

// Exact fp32 rerank, slab-parallel: task = (flagged row, 256-code slab).
__global__ __launch_bounds__(256) void rerank_kernel(
    const float* __restrict__ z, const float* __restrict__ en,
    const int* __restrict__ flagcnt, const int* __restrict__ flaglist,
    ull_t* __restrict__ pk) {
  __shared__ float sZ[512];
  __shared__ ull_t sk[4];
  const int t = threadIdx.x;
  const int w = t >> 6, lane = t & 63;
  int nf = *flagcnt;
  if (nf > BROWS) nf = BROWS;
  const int ntask = nf * 32;
  for (int task = blockIdx.x; task < ntask; task += gridDim.x) {
    const int f = task >> 5, slab = task & 31;
    const int row = flaglist[f];
    __syncthreads();
    if (t < 128) ((float4*)sZ)[t] = ((const float4*)(z + (size_t)row * DDIM))[t];
    __syncthreads();
    const float4 za = ((const float4*)sZ)[lane];
    const float4 zb = ((const float4*)sZ)[lane + 64];
    const int c0 = slab * 256 + w * 64;
    ull_t bk = 0;
    for (int cc = 0; cc < 64; ++cc) {
      const int c = c0 + cc;
      const float4* ep = (const float4*)(en + (size_t)c * DDIM);
      float4 ea = ep[lane], eb = ep[lane + 64];
      float d = ea.x*za.x + ea.y*za.y + ea.z*za.z + ea.w*za.w
              + eb.x*zb.x + eb.y*zb.y + eb.z*zb.z + eb.w*zb.w;
      d = wave_sum(d);
      ull_t k2 = pack_key(d, c);
      if (k2 > bk) bk = k2;
    }
    if (lane == 0) sk[w] = bk;
    __syncthreads();
    if (t == 0) {
      ull_t m = sk[0];
      if (sk[1] > m) m = sk[1];
      if (sk[2] > m) m = sk[2];
      if (sk[3] > m) m = sk[3];
      atomicMax(&pk[f], m);
    }
  }
}

__global__ __launch_bounds__(256) void unpack_kernel(
    const int* __restrict__ flagcnt, const int* __restrict__ flaglist,
    const ull_t* __restrict__ pk, int* __restrict__ idxs) {
  int nf = *flagcnt;
  if (nf > BROWS) nf = BROWS;
  for (int f = blockIdx.x * 256 + threadIdx.x; f < nf; f += gridDim.x * 256)
    idxs[flaglist[f]] = (NCODES - 1) - (int)(pk[f] & 0xFFFFFFFFu);
}

// finalize: per-block loss partial (no same-address global atomics).
__global__ __launch_bounds__(256) void finalize_kernel(const float* __restrict__ z,
                                                       const float* __restrict__ en,
                                                       const int* __restrict__ idxs,
                                                       float* __restrict__ out_q,
                                                       float* __restrict__ out_i,
                                                       float* __restrict__ counts,
                                                       float* __restrict__ lossp) {
  __shared__ float sdl[4];
  int w = threadIdx.x >> 6, lane = threadIdx.x & 63;
  int row = blockIdx.x * 4 + w;
  const float4* zr = (const float4*)(z + (size_t)row * DDIM);
  float4 a = zr[lane], b = zr[lane + 64];
  float s = a.x*a.x + a.y*a.y + a.z*a.z + a.w*a.w
          + b.x*b.x + b.y*b.y + b.z*b.z + b.w*b.w;
  s = wave_sum(s);
  float inv = 1.0f / fmaxf(sqrtf(s), 1e-12f);
  int k = idxs[row];
  const float4* qr = (const float4*)(en + (size_t)k * DDIM);
  float4 qa = qr[lane], qb = qr[lane + 64];
  float d = 0.0f;
  float4 oa, ob;
  {
    float zn;
    zn = a.x * inv; oa.x = zn + (qa.x - zn); d += (zn - qa.x) * (zn - qa.x);
    zn = a.y * inv; oa.y = zn + (qa.y - zn); d += (zn - qa.y) * (zn - qa.y);
    zn = a.z * inv; oa.z = zn + (qa.z - zn); d += (zn - qa.z) * (zn - qa.z);
    zn = a.w * inv; oa.w = zn + (qa.w - zn); d += (zn - qa.w) * (zn - qa.w);
    zn = b.x * inv; ob.x = zn + (qb.x - zn); d += (zn - qb.x) * (zn - qb.x);
    zn = b.y * inv; ob.y = zn + (qb.y - zn); d += (zn - qb.y) * (zn - qb.y);
    zn = b.z * inv; ob.z = zn + (qb.z - zn); d += (zn - qb.z) * (zn - qb.z);
    zn = b.w * inv; ob.w = zn + (qb.w - zn); d += (zn - qb.w) * (zn - qb.w);
  }
  float4* orow = (float4*)(out_q + (size_t)row * DDIM);
  orow[lane] = oa;
  orow[lane + 64] = ob;
  d = wave_sum(d);
  if (lane == 0) {
    sdl[w] = d;
    atomicAdd(&counts[k], 1.0f);
    out_i[row] = (float)k;
  }
  __syncthreads();
  if (threadIdx.x == 0)
    lossp[blockIdx.x] = sdl[0] + sdl[1] + sdl[2] + sdl[3];
}

__global__ __launch_bounds__(256) void scalars_kernel(const float* __restrict__ counts,
                                                      const float* __restrict__ lossp,
                                                      float* __restrict__ o) {
  __shared__ float se[256], su[256], sl[256];
  int t = threadIdx.x;
  float ent = 0.0f, utl = 0.0f, lsum = 0.0f;
  for (int i = t; i < NCODES; i += 256) {
    float c = counts[i];
    float p = c * (1.0f / (float)BROWS);
    ent -= p * logf(p + 1e-10f);
    utl += (c > 0.0f) ? 1.0f : 0.0f;
    lsum += lossp[i];
  }
  se[t] = ent; su[t] = utl; sl[t] = lsum;
  __syncthreads();
  for (int s2 = 128; s2 > 0; s2 >>= 1) {
    if (t < s2) { se[t] += se[t + s2]; su[t] += su[t + s2]; sl[t] += sl[t + s2]; }
    __syncthreads();
  }
  if (t == 0) {
    float mse = sl[0] * (1.0f / (float)(BROWS * DDIM));
    o[0] = 0.25f * mse;
    o[1] = mse;
    o[2] = expf(se[0]);
    o[3] = su[0] * (1.0f / (float)NCODES);
  }
}

// ---------- fallback (fp32 path, used only if ws too small) ----------
__global__ __launch_bounds__(256) void fb_norm_rows(const float* __restrict__ e,
                                                    float* __restrict__ en) {
  int w = threadIdx.x >> 6, lane = threadIdx.x & 63;
  int row = blockIdx.x * 4 + w;
  const float4* src = (const float4*)(e + (size_t)row * DDIM);
  float4 a = src[lane], b = src[lane + 64];
  float s = a.x*a.x + a.y*a.y + a.z*a.z + a.w*a.w
          + b.x*b.x + b.y*b.y + b.z*b.z + b.w*b.w;
  s = wave_sum(s);
  float inv = 1.0f / fmaxf(sqrtf(s), 1e-12f);
  float4* dst = (float4*)(en + (size_t)row * DDIM);
  dst[lane] = make_float4(a.x*inv, a.y*inv, a.z*inv, a.w*inv);
  dst[lane + 64] = make_float4(b.x*inv, b.y*inv, b.z*inv, b.w*inv);
}

__global__ __launch_bounds__(256) void fb_gemm_argmax(const float* __restrict__ z,
                                                      const float* __restrict__ en,
                                                      int* __restrict__ out_idx) {
  __shared__ float As[16][TM + 4];
  __shared__ float Bs[16][TN + 4];
  __shared__ float rv[TM][16];
  __shared__ int   ri[TM][16];
  const int t = threadIdx.x;
  const int tx = t & 15, ty = t >> 4;
  const int row0 = blockIdx.x * TM;
  const int m = t >> 2, f4 = t & 3;
  float bestv[8]; int bestn[8];
#pragma unroll
  for (int i = 0; i < 8; ++i) { bestv[i] = -3.0e38f; bestn[i] = 0; }
  for (int ct = 0; ct < NCODES / TN; ++ct) {
    float acc[8][8];
#pragma unroll
    for (int i = 0; i < 8; ++i)
#pragma unroll
      for (int j = 0; j < 8; ++j) acc[i][j] = 0.0f;
    for (int kt = 0; kt < DDIM / 16; ++kt) {
      const int k0 = kt * 16;
      __syncthreads();
      {
        const float* zb = z + (size_t)(row0 + m) * DDIM + k0 + f4 * 4;
        float4 v0 = *(const float4*)zb;
        float4 v1 = *(const float4*)(zb + (size_t)64 * DDIM);
        const float* ebp = en + (size_t)(ct * TN + m) * DDIM + k0 + f4 * 4;
        float4 w0 = *(const float4*)ebp;
        float4 w1 = *(const float4*)(ebp + (size_t)64 * DDIM);
        const int kk = f4 * 4;
        As[kk+0][m] = v0.x; As[kk+1][m] = v0.y; As[kk+2][m] = v0.z; As[kk+3][m] = v0.w;
        As[kk+0][m+64] = v1.x; As[kk+1][m+64] = v1.y; As[kk+2][m+64] = v1.z; As[kk+3][m+64] = v1.w;
        Bs[kk+0][m] = w0.x; Bs[kk+1][m] = w0.y; Bs[kk+2][m] = w0.z; Bs[kk+3][m] = w0.w;
        Bs[kk+0][m+64] = w1.x; Bs[kk+1][m+64] = w1.y; Bs[kk+2][m+64] = w1.z; Bs[kk+3][m+64] = w1.w;
      }
      __syncthreads();
#pragma unroll
      for (int k = 0; k < 16; ++k) {
        float4 a0 = *(const float4*)&As[k][ty * 8];
        float4 a1 = *(const float4*)&As[k][ty * 8 + 4];
        float4 b0 = *(const float4*)&Bs[k][tx * 4];
        float4 b1 = *(const float4*)&Bs[k][64 + tx * 4];
        float a[8] = {a0.x,a0.y,a0.z,a0.w,a1.x,a1.y,a1.z,a1.w};
        float b[8] = {b0.x,b0.y,b0.z,b0.w,b1.x,b1.y,b1.z,b1.w};
#pragma unroll
        for (int i = 0; i < 8; ++i)
#pragma unroll
          for (int j = 0; j < 8; ++j) acc[i][j] = fmaf(a[i], b[j], acc[i][j]);
      }
    }
    const int nb = ct * TN;
#pragma unroll
    for (int i = 0; i < 8; ++i)
#pragma unroll
      for (int j = 0; j < 8; ++j) {
        int n = nb + ((j < 4) ? (tx * 4 + j) : (64 + tx * 4 + (j - 4)));
        if (acc[i][j] > bestv[i]) { bestv[i] = acc[i][j]; bestn[i] = n; }
      }
  }
#pragma unroll
  for (int i = 0; i < 8; ++i) { rv[ty*8+i][tx] = bestv[i]; ri[ty*8+i][tx] = bestn[i]; }
  __syncthreads();
  if (t < TM) {
    float bv = rv[t][0]; int bi = ri[t][0];
#pragma unroll
    for (int x = 1; x < 16; ++x) {
      float v = rv[t][x]; int n = ri[t][x];
      if (v > bv || (v == bv && n < bi)) { bv = v; bi = n; }
    }
    out_idx[row0 + t] = bi;
  }
}

extern "C" void kernel_launch(void* const* d_in, const int* in_sizes, int n_in,
                              void* d_out, int out_size, void* d_ws, size_t ws_size,
                              hipStream_t stream) {
  const float* z = (const float*)d_in[0];
  const float* e = (const float*)d_in[1];
  float* out = (float*)d_out;
  float* ws = (float*)d_ws;

  float* out_q = out;
  float* out_i = out + (size_t)BROWS * DDIM;
  float* out_s = out_i + BROWS;

  const size_t ENF = (size_t)NCODES * DDIM;   // 4,194,304
  const size_t ZNF = (size_t)BROWS * DDIM;    // 16,777,216
  const size_t NFIN = BROWS / 4;              // 8192 finalize blocks

  // stage-2 compact buffers live in out_q (67 MB, dead until finalize).
  ushort_t* zhc = (ushort_t*)out_q;
  ushort_t* zlc = zhc + (size_t)NF_CAP * DDIM;

  // fast-path ws layout (float-unit offsets)
  size_t off = 0;
  float*    en       = ws + off;              off += ENF;
  ushort_t* enh      = (ushort_t*)(ws + off); off += ENF / 2;
  ushort_t* enl      = (ushort_t*)(ws + off); off += ENF / 2;
  ushort_t* zh       = (ushort_t*)(ws + off); off += ZNF / 2;
  ushort_t* zl       = (ushort_t*)(ws + off); off += ZNF / 2;
  float*    pv1      = ws + off;              off += (size_t)NCHUNK * BROWS;
  int*      pi1      = (int*)(ws + off);      off += (size_t)NCHUNK * BROWS;
  float*    pv2      = ws + off;              off += (size_t)NCHUNK * BROWS;
  float*    qv1      = ws + off;              off += (size_t)NSPLIT2 * NF_CAP;
  int*      qi1      = (int*)(ws + off);      off += (size_t)NSPLIT2 * NF_CAP;
  float*    qv2      = ws + off;              off += (size_t)NSPLIT2 * NF_CAP;
  int*      idxs     = (int*)(ws + off);      off += BROWS;
  int*      flaglist = (int*)(ws + off);      off += BROWS;
  int*      flag2list= (int*)(ws + off);      off += BROWS;
  float*    lossp    = ws + off;              off += NFIN;
  // zeroed region: counts | flagcnt | flag2cnt | pad | pk  (single memset)
  float*    counts   = ws + off;              off += NCODES;
  int*      flagcnt  = (int*)(ws + off);      off += 1;
  int*      flag2cnt = (int*)(ws + off);      off += 1;
  if (off & 1) off += 1;                      // 8B-align pk
  ull_t*    pk       = (ull_t*)(ws + off);    off += (size_t)BROWS * 2;
  const size_t need_bytes = off * sizeof(float);
  const size_t zero_bytes = (size_t)((char*)(pk + BROWS) - (char*)counts);

  if (ws_size >= need_bytes) {
    prep_split_kernel<<<NCODES / 4, 256, 0, stream>>>(e, en, enh, enl);
    prep_split_kernel<<<BROWS / 4, 256, 0, stream>>>(z, nullptr, zh, zl);
    hipMemsetAsync(counts, 0, zero_bytes, stream);
    dim3 g1(NCHUNK, BROWS / TM);
    gemm1_kernel<<<g1, 256, 0, stream>>>(zh, enh, pv1, pi1, pv2);
    combine1_kernel<<<BROWS / 256, 256, 0, stream>>>(pv1, pi1, pv2, idxs, flagcnt, flaglist);
    compact_kernel<<<NF_CAP / 4, 256, 0, stream>>>(zh, zl, flagcnt, flaglist, zhc, zlc);
    dim3 g2(NSPLIT2, NF_CAP / TM);
    gemm3f_kernel<<<g2, 256, 0, stream>>>(zhc, zlc, enh, enl, flagcnt, qv1, qi1, qv2);
    combine2_kernel<<<NF_CAP / 256, 256, 0, stream>>>(qv1, qi1, qv2, flagcnt, flaglist,
                                                      idxs, flag2cnt, flag2list);
    rerank_kernel<<<1024, 256, 0, stream>>>(z, en, flag2cnt, flag2list, pk);
    unpack_kernel<<<32, 256, 0, stream>>>(flag2cnt, flag2list, pk, idxs);
    finalize_kernel<<<BROWS / 4, 256, 0, stream>>>(z, en, idxs, out_q, out_i, counts, lossp);
    scalars_kernel<<<1, 256, 0, stream>>>(counts, lossp, out_s);
  } else {
    // fallback: fp32 path (~17 MB ws)
    float* fen    = ws;
    int*   fidx   = (int*)(fen + ENF);
    float* fcnt   = (float*)(fidx + BROWS);
    float* flossp = fcnt + NCODES;
    fb_norm_rows<<<NCODES / 4, 256, 0, stream>>>(e, fen);
    hipMemsetAsync(fcnt, 0, NCODES * sizeof(float), stream);
    fb_gemm_argmax<<<BROWS / TM, 256, 0, stream>>>(z, fen, fidx);
    finalize_kernel<<<BROWS / 4, 256, 0, stream>>>(z, fen, fidx, out_q, out_i, fcnt, flossp);
    scalars_kernel<<<1, 256, 0, stream>>>(fcnt, flossp, out_s);
  }
}